// Round 11
// baseline (967.677 us; speedup 1.0000x reference)
//
#include <hip/hip_runtime.h>

constexpr int S = 4096, M = 512, E = 16, CC = 128;
constexpr int H1 = 500, H2 = 500, H3 = 2000;
constexpr int NB = 512;    // grid blocks (2 per CU, guaranteed resident)
constexpr int NT = 256;    // threads per block
constexpr int TB = 256;    // mmd tile size

struct P0m { float vsh[4][16]; float sp[16]; };
struct P1m { int rsi[512]; float rsg[512]; float sw[4][32]; float sw2[4][32]; int sc[4][32]; };
struct P6m { float Es[32 * 132]; float Gs[1024]; int cpl[1024]; double redd[256];
             float wf[32], w2f[32]; int tot[32], offmy[32], wcnt[4][32]; float dpl[16]; float c; };
struct P7m { float K2[1056]; float gA[264], aA[264], sA[264]; int eA[264];
             float gB[264], aB[264], sB[264]; int eB[264]; float wred[4]; };
struct P8m { double redd[256]; };
union SMem { P0m p0; P1m p1; P6m p6; P7m p7; P8m p8; };

// resident-grid barrier: fresh counter per phase (memset-zeroed each launch)
__device__ inline void gsync(int* cnt, int phase) {
  __syncthreads();
  __threadfence();                                   // release: XCD L2 writeback
  if (threadIdx.x == 0) {
    atomicAdd(&cnt[phase], 1);                       // device scope
    while (__hip_atomic_load(&cnt[phase], __ATOMIC_RELAXED, __HIP_MEMORY_SCOPE_AGENT) < NB)
      __builtin_amdgcn_s_sleep(2);
  }
  __syncthreads();
  __threadfence();                                   // acquire: invalidate stale lines
}

__global__ __launch_bounds__(NT, 2) void k_mega(
    const float* __restrict__ x, const float* __restrict__ noise, const float* __restrict__ Wr,
    const float* __restrict__ W1, const float* __restrict__ b1,
    const float* __restrict__ W2, const float* __restrict__ b2,
    const float* __restrict__ W3, const float* __restrict__ b3,
    const float* __restrict__ W4, const float* __restrict__ b4,
    const int* __restrict__ idx1, const int* __restrict__ idx2,
    int* i0, int* i1, float* g0, float* g1, float* selpart,
    float* gpart, float* ei, float* h1, float* h2, float* h3, float* eo,
    float* G32, float* rowg, int* rowe, float* wpart, int* cpart,
    float* srowg, float* srowA, int* srowe, float* srowsg, float* cl2,
    double* bsum, int* cnt,
    float* out, float* out_sel0, float* out_bal, float* out_dist,
    int ns, int ncnt, int npad, int nt, int ntri, int nrowblk) {
  __shared__ SMem sm;
  const int t = threadIdx.x, blk = blockIdx.x;
  const int lane = t & 63, wid = t >> 6;

  // ---------------- P0: route (8 tokens per block) ----------------
  {
    if (t < 16) sm.p0.sp[t] = 0.f;
    __syncthreads();
    for (int it = 0; it < 2; ++it) {
      int s = blk * 8 + it * 4 + wid;
      const float* xr = x + (size_t)s * M;
      float xv[8];
#pragma unroll
      for (int c = 0; c < 8; ++c) xv[c] = xr[lane + 64 * c];
      float v[E];
#pragma unroll
      for (int e = 0; e < E; ++e) {
        const float* wr = Wr + (size_t)e * M;
        float acc = 0.f;
#pragma unroll
        for (int c = 0; c < 8; ++c) acc = fmaf(xv[c], wr[lane + 64 * c], acc);
#pragma unroll
        for (int off = 32; off; off >>= 1) acc += __shfl_xor(acc, off);
        v[e] = acc + noise[s * E + e];
      }
      int a0 = 0; float m0 = v[0];
#pragma unroll
      for (int e = 1; e < E; ++e) if (v[e] > m0) { m0 = v[e]; a0 = e; }
      int a1 = -1; float m1 = -3.4e38f;
#pragma unroll
      for (int e = 0; e < E; ++e) if (e != a0 && v[e] > m1) { m1 = v[e]; a1 = e; }
      if (lane == 0) { i0[s] = a0; i1[s] = a1; g0[s] = m0; g1[s] = m1; }
      if (lane < 16) {
        int e = lane;
        out_sel0[(size_t)s * 32 + e * 2 + 0] = (e == a0 && m0 != 0.f) ? 1.f : 0.f;
        out_sel0[(size_t)s * 32 + e * 2 + 1] = (e == a1 && m1 != 0.f) ? 1.f : 0.f;
        sm.p0.vsh[wid][lane] = v[lane];
      }
      __syncthreads();
      if (t < 16) sm.p0.sp[t] += sm.p0.vsh[0][t] + sm.p0.vsh[1][t] + sm.p0.vsh[2][t] + sm.p0.vsh[3][t];
      __syncthreads();
    }
    if (t < 16) selpart[blk * 16 + t] = sm.p0.sp[t];
  }
  gsync(cnt, 0);

  // ------------- P1: segmented gather partials + row scalars -------------
  {
    int seg = blk & 7, half = (blk >> 3) & 1, ek = blk >> 4;   // 32*2*8 = 512
    int k = ek & 1, e = ek >> 1;
    const int* route = k ? i1 : i0;
    const float* gg = k ? g1 : g0;
    int s0 = seg * 512;
    sm.p1.rsi[t] = route[s0 + t];         sm.p1.rsi[t + 256] = route[s0 + t + 256];
    sm.p1.rsg[t] = gg[s0 + t];            sm.p1.rsg[t + 256] = gg[s0 + t + 256];
    __syncthreads();
    int d = half * 256 + t;
    float acc = 0.f;
    for (int q = 0; q < 512; ++q) {
      if (sm.p1.rsi[q] == e && sm.p1.rsg[q] != 0.f) acc += x[(size_t)(s0 + q) * M + d];
    }
    gpart[(size_t)seg * (32 * M) + ek * M + d] = acc;
    __syncthreads();
    if (blk < nrowblk) {                  // row scalars + per-ek w/w2/count partials
      int r = blk * 256 + t;
      float g = 0.f; int ekr = 0;
      if (r < ns)        { int tk = idx1[r];      ekr = i0[tk] * 2 + 0; g = g0[tk]; }
      else if (r < ncnt) { int tk = idx2[r - ns]; ekr = i1[tk] * 2 + 1; g = g1[tk]; }
      rowg[r] = g; rowe[r] = ekr;
      float g2 = g * g;
      for (int e2 = 0; e2 < 32; ++e2) {
        unsigned long long m = __ballot(ekr == e2);
        float vw = (ekr == e2) ? g : 0.f;
        float vw2 = (ekr == e2) ? g2 : 0.f;
#pragma unroll
        for (int off = 32; off; off >>= 1) { vw += __shfl_xor(vw, off); vw2 += __shfl_xor(vw2, off); }
        if (lane == 0) { sm.p1.sw[wid][e2] = vw; sm.p1.sw2[wid][e2] = vw2; sm.p1.sc[wid][e2] = __popcll(m); }
      }
      __syncthreads();
      if (t < 32) {
        wpart[blk * 64 + t]      = sm.p1.sw[0][t] + sm.p1.sw[1][t] + sm.p1.sw[2][t] + sm.p1.sw[3][t];
        wpart[blk * 64 + 32 + t] = sm.p1.sw2[0][t] + sm.p1.sw2[1][t] + sm.p1.sw2[2][t] + sm.p1.sw2[3][t];
        cpart[blk * 32 + t]      = sm.p1.sc[0][t] + sm.p1.sc[1][t] + sm.p1.sc[2][t] + sm.p1.sc[3][t];
      }
    }
  }
  gsync(cnt, 1);

  // ---------------- P2a: ei = fixed-order 8-way reduce ----------------
  {
    int idx = blk * NT + t;
    if (idx < E * 2 * M) {
      float acc = 0.f;
#pragma unroll
      for (int sg = 0; sg < 8; ++sg) acc += gpart[(size_t)sg * (32 * M) + idx];
      ei[idx] = acc;
    }
  }
  gsync(cnt, 2);

  // ---------------- P2b..P5: MLP layers (grid-stride GEMV) ----------------
  {
    int wg = blk * 4 + wid;
    for (int task = wg; task < E * H1; task += NB * 4) {
      int e = task / H1;
      const float* wr = W1 + (size_t)task * M;
      const float* in0 = ei + (size_t)(e * 2 + 0) * M;
      const float* in1 = ei + (size_t)(e * 2 + 1) * M;
      float a0 = 0.f, a1 = 0.f;
      for (int m = lane; m < M; m += 64) { float wv = wr[m]; a0 += wv * in0[m]; a1 += wv * in1[m]; }
#pragma unroll
      for (int off = 32; off; off >>= 1) { a0 += __shfl_xor(a0, off); a1 += __shfl_xor(a1, off); }
      if (lane == 0) {
        float bb = b1[task];
        h1[(size_t)(e * 2 + 0) * H1 + (task - e * H1)] = fmaxf(a0 + bb, 0.f);
        h1[(size_t)(e * 2 + 1) * H1 + (task - e * H1)] = fmaxf(a1 + bb, 0.f);
      }
    }
  }
  gsync(cnt, 3);
  {
    int wg = blk * 4 + wid;
    for (int task = wg; task < E * H2; task += NB * 4) {
      int e = task / H2;
      const float* wr = W2 + (size_t)task * H1;
      const float* in0 = h1 + (size_t)(e * 2 + 0) * H1;
      const float* in1 = h1 + (size_t)(e * 2 + 1) * H1;
      float a0 = 0.f, a1 = 0.f;
      for (int m = lane; m < H1; m += 64) { float wv = wr[m]; a0 += wv * in0[m]; a1 += wv * in1[m]; }
#pragma unroll
      for (int off = 32; off; off >>= 1) { a0 += __shfl_xor(a0, off); a1 += __shfl_xor(a1, off); }
      if (lane == 0) {
        float bb = b2[task];
        h2[(size_t)(e * 2 + 0) * H2 + (task - e * H2)] = fmaxf(a0 + bb, 0.f);
        h2[(size_t)(e * 2 + 1) * H2 + (task - e * H2)] = fmaxf(a1 + bb, 0.f);
      }
    }
  }
  gsync(cnt, 4);
  {
    int wg = blk * 4 + wid;
    for (int task = wg; task < E * H3; task += NB * 4) {
      int e = task / H3;
      const float* wr = W3 + (size_t)task * H2;
      const float* in0 = h2 + (size_t)(e * 2 + 0) * H2;
      const float* in1 = h2 + (size_t)(e * 2 + 1) * H2;
      float a0 = 0.f, a1 = 0.f;
      for (int m = lane; m < H2; m += 64) { float wv = wr[m]; a0 += wv * in0[m]; a1 += wv * in1[m]; }
#pragma unroll
      for (int off = 32; off; off >>= 1) { a0 += __shfl_xor(a0, off); a1 += __shfl_xor(a1, off); }
      if (lane == 0) {
        float bb = b3[task];
        h3[(size_t)(e * 2 + 0) * H3 + (task - e * H3)] = fmaxf(a0 + bb, 0.f);
        h3[(size_t)(e * 2 + 1) * H3 + (task - e * H3)] = fmaxf(a1 + bb, 0.f);
      }
    }
  }
  gsync(cnt, 5);
  {
    int wg = blk * 4 + wid;
    for (int task = wg; task < E * CC; task += NB * 4) {
      int e = task / CC;
      const float* wr = W4 + (size_t)task * H3;
      const float* in0 = h3 + (size_t)(e * 2 + 0) * H3;
      const float* in1 = h3 + (size_t)(e * 2 + 1) * H3;
      float a0 = 0.f, a1 = 0.f;
      for (int m = lane; m < H3; m += 64) { float wv = wr[m]; a0 += wv * in0[m]; a1 += wv * in1[m]; }
#pragma unroll
      for (int off = 32; off; off >>= 1) { a0 += __shfl_xor(a0, off); a1 += __shfl_xor(a1, off); }
      if (lane == 0) {
        float bb = b4[task];
        eo[(size_t)(e * 2 + 0) * CC + (task - e * CC)] = a0 + bb;
        eo[(size_t)(e * 2 + 1) * CC + (task - e * CC)] = a1 + bb;
      }
    }
  }
  gsync(cnt, 6);

  // ------- P6: Gram + cl + expert-sort (blocks 0..nrowblk-1); balance (block nrowblk) -------
  if (blk < nrowblk) {
    for (int i = t; i < 32 * 128; i += 256) sm.p6.Es[(i >> 7) * 132 + (i & 127)] = eo[i];
    __syncthreads();
    for (int p = t; p < 1024; p += 256) {
      int u = p >> 5, v = p & 31;
      float s = 0.f;
#pragma unroll 8
      for (int d = 0; d < 128; ++d) s = fmaf(sm.p6.Es[u * 132 + d], sm.p6.Es[v * 132 + d], s);
      sm.p6.Gs[p] = s;
      if (blk == 0) G32[p] = s;
    }
    for (int i = t; i < nrowblk * 32; i += 256) sm.p6.cpl[i] = cpart[i];
    if (t < 32) {
      float sw = 0.f, sw2 = 0.f;
      for (int b = 0; b < nrowblk; ++b) { sw += wpart[b * 64 + t]; sw2 += wpart[b * 64 + 32 + t]; }
      sm.p6.wf[t] = sw; sm.p6.w2f[t] = sw2;
    }
    __syncthreads();
    if (t < 32) {
      int tot = 0;
      for (int b = 0; b < nrowblk; ++b) tot += sm.p6.cpl[b * 32 + t];
      sm.p6.tot[t] = tot;
    }
    __syncthreads();
    if (t < 32) {
      int off = 0;
      for (int e = 0; e < t; ++e) off += sm.p6.tot[e];
      for (int b = 0; b < blk; ++b) off += sm.p6.cpl[b * 32 + t];
      sm.p6.offmy[t] = off;
    }
    double part = 0.0;
    for (int i = t; i < 1024; i += 256)
      part += (double)sm.p6.wf[i >> 5] * (double)sm.p6.wf[i & 31] * (double)sm.p6.Gs[i];
    sm.p6.redd[t] = part;
    __syncthreads();
    for (int off = 128; off; off >>= 1) { if (t < off) sm.p6.redd[t] += sm.p6.redd[t + off]; __syncthreads(); }
    double wGw = sm.p6.redd[0];
    __syncthreads();
    sm.p6.redd[t] = (t < 32) ? (double)sm.p6.w2f[t] * (double)sm.p6.Gs[t * 33] : 0.0;
    __syncthreads();
    for (int off = 128; off; off >>= 1) { if (t < off) sm.p6.redd[t] += sm.p6.redd[t + off]; __syncthreads(); }
    if (t == 0) {
      double nn = (double)ncnt;
      double sumd2 = 2.0 * nn * sm.p6.redd[0] - 2.0 * wGw;
      double bw = sumd2 / (nn * nn - nn) / 4.0;
      sm.p6.c = (float)(1.0 / (bw * 16.0));
      if (blk == 0) cl2[0] = sm.p6.c;
    }
    __syncthreads();
    float c = sm.p6.c;
    int r = blk * 256 + t;
    float g = rowg[r]; int ekr = rowe[r];
    float sg = (r < ns) ? 1.f : (r < ncnt ? -1.f : 0.f);
    int myrank = 0;
    for (int e = 0; e < 32; ++e) {
      unsigned long long m = __ballot(ekr == e);
      if (ekr == e) myrank = __popcll(m & ((1ull << lane) - 1ull));
      if (lane == 0) sm.p6.wcnt[wid][e] = __popcll(m);
    }
    __syncthreads();
    int woff = 0;
    for (int w2 = 0; w2 < wid; ++w2) woff += sm.p6.wcnt[w2][ekr];
    int dest = sm.p6.offmy[ekr] + woff + myrank;
    srowg[dest] = g;
    srowsg[dest] = sg;
    srowe[dest] = ekr;
    srowA[dest] = c * g * g * sm.p6.Gs[ekr * 33];
  } else if (blk == nrowblk) {
    // balance loss
    int e2 = t & 15, r0 = t >> 4;
    double acc = 0.0;
    for (int b2 = r0; b2 < NB; b2 += 16) acc += (double)selpart[b2 * 16 + e2];
    sm.p6.redd[t] = acc;
    __syncthreads();
    for (int off = 128; off >= 16; off >>= 1) { if (t < off) sm.p6.redd[t] += sm.p6.redd[t + off]; __syncthreads(); }
    if (t < 16) sm.p6.dpl[t] = (float)(sm.p6.redd[t] / (double)S);
    __syncthreads();
    double acc2 = 0.0;
    for (int s2 = t; s2 < S; s2 += 256) acc2 += 0.5 * ((double)sm.p6.dpl[i0[s2]] + (double)sm.p6.dpl[i1[s2]]);
    sm.p6.redd[t] = acc2;
    __syncthreads();
    for (int off = 128; off; off >>= 1) { if (t < off) sm.p6.redd[t] += sm.p6.redd[t + off]; __syncthreads(); }
    if (t == 0) out_bal[0] = (float)(sm.p6.redd[0] / 256.0);
  }
  gsync(cnt, 7);

  // ---------------- P7: token output + mmd tiles ----------------
  {
#pragma unroll
    for (int ii = 0; ii < 4; ++ii) {
      int idx = blk * 1024 + ii * 256 + t;
      int s = idx >> 7, d = idx & (CC - 1);
      out[idx] = g0[s] * eo[(i0[s] * 2 + 0) * CC + d] + g1[s] * eo[(i1[s] * 2 + 1) * CC + d];
    }
  }
  if (blk < ntri) {
    int bi = 0, rem = blk;
    while (rem >= nt - bi) { rem -= nt - bi; ++bi; }
    int bj = bi + rem;
    const int ib = bi * TB, jb = bj * TB;
    float c = cl2[0];
    for (int i = t; i < 1024; i += 256) sm.p7.K2[(i >> 5) * 33 + (i & 31)] = 2.f * c * G32[i];
    {
      int p = (t & 7) * 33 + (t >> 3);
      sm.p7.gA[p] = srowg[ib + t]; sm.p7.aA[p] = srowA[ib + t];
      sm.p7.eA[p] = srowe[ib + t] * 33; sm.p7.sA[p] = srowsg[ib + t];
      sm.p7.gB[p] = srowg[jb + t]; sm.p7.aB[p] = srowA[jb + t];
      sm.p7.eB[p] = srowe[jb + t]; sm.p7.sB[p] = srowsg[jb + t];
    }
    __syncthreads();
    int ti = t & 15, tj = t >> 4;
    float gi[16], Ai[16], sgi[16]; int exi[16];
#pragma unroll
    for (int r = 0; r < 16; ++r) {
      int p = (r & 7) * 33 + ti * 2 + (r >> 3);
      gi[r] = sm.p7.gA[p]; Ai[r] = sm.p7.aA[p]; exi[r] = sm.p7.eA[p]; sgi[r] = sm.p7.sA[p];
    }
    float tsum = 0.f;
#pragma unroll
    for (int cb = 0; cb < 2; ++cb) {
      float gj[8], Aj[8], sgj[8]; int exj[8];
#pragma unroll
      for (int q = 0; q < 8; ++q) {
        int p = q * 33 + tj * 2 + cb;
        gj[q] = sm.p7.gB[p]; Aj[q] = sm.p7.aB[p]; exj[q] = sm.p7.eB[p]; sgj[q] = sm.p7.sB[p];
      }
#pragma unroll
      for (int r = 0; r < 16; ++r) {
#pragma unroll
        for (int q = 0; q < 8; ++q) {
          float gg = gi[r] * gj[q];
          float arg = fmaf(sm.p7.K2[exi[r] + exj[q]], gg, -(Ai[r] + Aj[q]));
          float tv = __expf(arg);
          float t2 = tv * tv;  float s5 = tv + t2;
          float t4 = t2 * t2;  s5 += t4;
          float t8 = t4 * t4;  s5 += t8;
          float t16 = t8 * t8; s5 += t16;
          tsum = fmaf(sgi[r] * sgj[q], s5, tsum);
        }
      }
    }
#pragma unroll
    for (int off = 32; off; off >>= 1) tsum += __shfl_xor(tsum, off);
    if (lane == 0) sm.p7.wred[wid] = tsum;
    __syncthreads();
    if (t == 0) {
      float sblk = sm.p7.wred[0] + sm.p7.wred[1] + sm.p7.wred[2] + sm.p7.wred[3];
      bsum[blk] = (double)sblk * ((bi == bj) ? 1.0 : 2.0);
    }
  }
  gsync(cnt, 8);

  // ---------------- P8: final reduce (block 0, fixed order) ----------------
  if (blk == 0) {
    double acc = 0.0;
    for (int i = t; i < ntri; i += 256) acc += bsum[i];
    sm.p8.redd[t] = acc;
    __syncthreads();
    for (int off = 128; off; off >>= 1) { if (t < off) sm.p8.redd[t] += sm.p8.redd[t + off]; __syncthreads(); }
    if (t == 0) out_dist[0] = (float)(-sm.p8.redd[0] / ((double)ns * (double)ns));
  }
}

extern "C" void kernel_launch(void* const* d_in, const int* in_sizes, int n_in,
                              void* d_out, int out_size, void* d_ws, size_t ws_size,
                              hipStream_t stream) {
  const float* x  = (const float*)d_in[0];
  const float* noise = (const float*)d_in[1];
  const float* Wr = (const float*)d_in[2];
  const float* W1 = (const float*)d_in[3];
  const float* b1 = (const float*)d_in[4];
  const float* W2 = (const float*)d_in[5];
  const float* b2 = (const float*)d_in[6];
  const float* W3 = (const float*)d_in[7];
  const float* b3 = (const float*)d_in[8];
  const float* W4 = (const float*)d_in[9];
  const float* b4 = (const float*)d_in[10];
  const int* idx1 = (const int*)d_in[11];
  const int* idx2 = (const int*)d_in[12];
  int ns = in_sizes[11];
  int n = 2 * ns;
  int npad = (n + 255) & ~255;
  int nt = npad / TB;
  int ntri = nt * (nt + 1) / 2;
  int nrowblk = npad / 256;

  char* wp = (char*)d_ws;
  size_t off = 0;
  auto alloc = [&](size_t bytes) -> void* {
    void* p = wp + off;
    off += (bytes + 255) & ~(size_t)255;
    return p;
  };
  int*   i0  = (int*)alloc((size_t)S * 4);
  int*   i1  = (int*)alloc((size_t)S * 4);
  float* g0  = (float*)alloc((size_t)S * 4);
  float* g1  = (float*)alloc((size_t)S * 4);
  float* selpart = (float*)alloc((size_t)NB * 16 * 4);
  float* gpart = (float*)alloc((size_t)8 * 32 * M * 4);
  float* ei  = (float*)alloc((size_t)E * 2 * M * 4);
  float* h1  = (float*)alloc((size_t)E * 2 * H1 * 4);
  float* h2  = (float*)alloc((size_t)E * 2 * H2 * 4);
  float* h3  = (float*)alloc((size_t)E * 2 * H3 * 4);
  float* eo  = (float*)alloc((size_t)E * 2 * CC * 4);
  float* G32 = (float*)alloc((size_t)1024 * 4);
  float* rowg = (float*)alloc((size_t)npad * 4);
  int*   rowe = (int*)alloc((size_t)npad * 4);
  float* wpart = (float*)alloc((size_t)nrowblk * 64 * 4);
  int*   cpart = (int*)alloc((size_t)nrowblk * 32 * 4);
  float* srowg = (float*)alloc((size_t)npad * 4);
  float* srowA = (float*)alloc((size_t)npad * 4);
  int*   srowe = (int*)alloc((size_t)npad * 4);
  float* srowsg = (float*)alloc((size_t)npad * 4);
  float* cl2 = (float*)alloc(16);
  double* bsum = (double*)alloc((size_t)ntri * 8);
  int* counters = (int*)alloc(256);
  (void)ws_size; (void)n_in; (void)out_size;

  float* out      = (float*)d_out;
  float* out_sel0 = out + (size_t)S * CC;
  float* out_bal  = out + (size_t)S * CC + (size_t)S * E * 2;
  float* out_dist = out_bal + 1;

  hipMemsetAsync(counters, 0, 64, stream);
  k_mega<<<NB, NT, 0, stream>>>(x, noise, Wr, W1, b1, W2, b2, W3, b3, W4, b4, idx1, idx2,
                                i0, i1, g0, g1, selpart, gpart, ei, h1, h2, h3, eo,
                                G32, rowg, rowe, wpart, cpart,
                                srowg, srowA, srowe, srowsg, cl2, bsum, counters,
                                out, out_sel0, out_bal, out_dist,
                                ns, n, npad, nt, ntri, nrowblk);
}

// Round 12
// 135.449 us; speedup vs baseline: 7.1442x; 7.1442x over previous
//
#include <hip/hip_runtime.h>

constexpr int S = 4096, M = 512, E = 16, CC = 128;
constexpr int H1 = 500, H2 = 500, H3 = 2000;
constexpr int TB = 256;   // mmd tile size

// fused: select = x@Wr^T + noise; top2; sel0 output; per-block column partials; zero counter
__global__ void k_route(const float* __restrict__ x, const float* __restrict__ noise,
                        const float* __restrict__ Wr, int* __restrict__ i0, int* __restrict__ i1,
                        float* __restrict__ g0, float* __restrict__ g1,
                        float* __restrict__ sel0, float* __restrict__ selpart,
                        int* __restrict__ counters) {
  if (blockIdx.x == 0 && threadIdx.x == 0) { counters[0] = 0; }
  int wid = threadIdx.x >> 6, lane = threadIdx.x & 63;
  int s = blockIdx.x * 4 + wid;
  const float* xr = x + (size_t)s * M;
  float xv[8];
#pragma unroll
  for (int c = 0; c < 8; ++c) xv[c] = xr[lane + 64 * c];
  float v[E];
#pragma unroll
  for (int e = 0; e < E; ++e) {
    const float* wr = Wr + (size_t)e * M;
    float acc = 0.f;
#pragma unroll
    for (int c = 0; c < 8; ++c) acc = fmaf(xv[c], wr[lane + 64 * c], acc);
#pragma unroll
    for (int off = 32; off; off >>= 1) acc += __shfl_xor(acc, off);
    v[e] = acc + noise[s * E + e];
  }
  int a0 = 0; float m0 = v[0];
#pragma unroll
  for (int e = 1; e < E; ++e) if (v[e] > m0) { m0 = v[e]; a0 = e; }
  int a1 = -1; float m1 = -3.4e38f;
#pragma unroll
  for (int e = 0; e < E; ++e) if (e != a0 && v[e] > m1) { m1 = v[e]; a1 = e; }
  __shared__ float vsh[4][16];
  if (lane < 16) vsh[wid][lane] = v[lane];
  if (lane == 0) { i0[s] = a0; i1[s] = a1; g0[s] = m0; g1[s] = m1; }
  if (lane < 16) {
    int e = lane;
    sel0[(size_t)s * 32 + e * 2 + 0] = (e == a0 && m0 != 0.f) ? 1.f : 0.f;
    sel0[(size_t)s * 32 + e * 2 + 1] = (e == a1 && m1 != 0.f) ? 1.f : 0.f;
  }
  __syncthreads();
  if (threadIdx.x < 16) {
    int e = threadIdx.x;
    selpart[blockIdx.x * 16 + e] = vsh[0][e] + vsh[1][e] + vsh[2][e] + vsh[3][e];
  }
}

// balance_loss from column partials. Single block, deterministic.
__global__ void k_balance(const float* __restrict__ selpart, const int* __restrict__ i0,
                          const int* __restrict__ i1, float* __restrict__ outb) {
  __shared__ double part[512];
  __shared__ float dpl[E];
  int t = threadIdx.x;
  int e = t & 15, r0 = t >> 4;
  double acc = 0.0;
  for (int b = r0; b < 1024; b += 32) acc += (double)selpart[b * 16 + e];
  part[t] = acc;
  __syncthreads();
  for (int off = 256; off >= 16; off >>= 1) {
    if (t < off) part[t] += part[t + off];
    __syncthreads();
  }
  if (t < E) dpl[t] = (float)(part[t] / (double)S);
  __syncthreads();
  double acc2 = 0.0;
  for (int s = t; s < S; s += 512) acc2 += 0.5 * ((double)dpl[i0[s]] + (double)dpl[i1[s]]);
  part[t] = acc2;
  __syncthreads();
  for (int off = 256; off; off >>= 1) {
    if (t < off) part[t] += part[t + off];
    __syncthreads();
  }
  if (t == 0) outb[0] = (float)(part[0] / 256.0);
}

// compact token lists per (e,k), order-preserving (deterministic)
__global__ void k_lists(const int* __restrict__ i0, const int* __restrict__ i1,
                        const float* __restrict__ g0, const float* __restrict__ g1,
                        int* __restrict__ list, int* __restrict__ cnt) {
  int ek = blockIdx.x;
  int k = ek & 1, e = ek >> 1;
  const int* route = k ? i1 : i0;
  const float* gg = k ? g1 : g0;
  __shared__ int base_s;
  __shared__ int wsum[4];
  int t = threadIdx.x;
  int lane = t & 63, w = t >> 6;
  if (t == 0) base_s = 0;
  __syncthreads();
  for (int s0 = 0; s0 < S; s0 += 256) {
    int s = s0 + t;
    bool flag = (route[s] == e) && (gg[s] != 0.f);
    unsigned long long m = __ballot(flag);
    int within = __popcll(m & ((1ull << lane) - 1ull));
    if (lane == 0) wsum[w] = __popcll(m);
    __syncthreads();
    int wbase = base_s;
    for (int i = 0; i < w; ++i) wbase += wsum[i];
    if (flag) list[ek * S + wbase + within] = s;
    __syncthreads();
    if (t == 0) base_s += wsum[0] + wsum[1] + wsum[2] + wsum[3];
    __syncthreads();
  }
  if (t == 0) cnt[ek] = base_s;
}

// 8-way segmented gather partials (by list stride)
__global__ void k_gather(const float* __restrict__ x, const int* __restrict__ list,
                         const int* __restrict__ cnt, float* __restrict__ gpart) {
  int b = blockIdx.x;                  // 1024 = ek(32)*chunk(4)*seg(8)
  int seg = b & 7, chunk = (b >> 3) & 3, ek = b >> 5;
  int t = threadIdx.x;                 // 128
  int d = chunk * 128 + t;
  int nl = cnt[ek];
  const int* lp = list + ek * S;
  float acc = 0.f;
  int q = seg;
  for (; q + 24 < nl; q += 32) {
    int s0 = lp[q], s1 = lp[q + 8], s2 = lp[q + 16], s3 = lp[q + 24];
    acc += x[(size_t)s0 * M + d];
    acc += x[(size_t)s1 * M + d];
    acc += x[(size_t)s2 * M + d];
    acc += x[(size_t)s3 * M + d];
  }
  for (; q < nl; q += 8) acc += x[(size_t)lp[q] * M + d];
  gpart[(size_t)seg * (32 * M) + ek * M + d] = acc;
}

__global__ void k_gather_red(const float* __restrict__ gpart, float* __restrict__ ei) {
  int idx = blockIdx.x * blockDim.x + threadIdx.x;   // 16384
  float acc = 0.f;
#pragma unroll
  for (int sg = 0; sg < 8; ++sg) acc += gpart[(size_t)sg * (32 * M) + idx];
  ei[idx] = acc;
}

// generic MLP layer: wave per (e,h) output neuron, both k rows at once
template <int DIN, int HOUT, bool RELU>
__global__ void k_layer(const float* __restrict__ in, const float* __restrict__ W,
                        const float* __restrict__ bias, float* __restrict__ out) {
  int w = (blockIdx.x * blockDim.x + threadIdx.x) >> 6;
  int lane = threadIdx.x & 63;
  if (w >= E * HOUT) return;
  int e = w / HOUT, h = w - e * HOUT;
  const float* wr = W + ((size_t)e * HOUT + h) * DIN;
  const float* in0 = in + (size_t)(e * 2 + 0) * DIN;
  const float* in1 = in + (size_t)(e * 2 + 1) * DIN;
  float a0 = 0.f, a1 = 0.f;
  for (int m = lane; m < DIN; m += 64) {
    float wv = wr[m];
    a0 += wv * in0[m];
    a1 += wv * in1[m];
  }
#pragma unroll
  for (int off = 32; off; off >>= 1) {
    a0 += __shfl_xor(a0, off);
    a1 += __shfl_xor(a1, off);
  }
  if (lane == 0) {
    float bb = bias[e * HOUT + h];
    float o0 = a0 + bb, o1 = a1 + bb;
    if (RELU) { o0 = fmaxf(o0, 0.f); o1 = fmaxf(o1, 0.f); }
    out[(size_t)(e * 2 + 0) * HOUT + h] = o0;
    out[(size_t)(e * 2 + 1) * HOUT + h] = o1;
  }
}

// 32x32 Gram of the expert-output base rows
__global__ void k_G(const float* __restrict__ eo, float* __restrict__ G32) {
  __shared__ float Es[32][129];
  int t = threadIdx.x;  // 256
  for (int i = t; i < 32 * 128; i += 256) Es[i >> 7][i & 127] = eo[i];
  __syncthreads();
  for (int p = t; p < 1024; p += 256) {
    int u = p >> 5, v = p & 31;
    float s = 0.f;
#pragma unroll 8
    for (int d = 0; d < 128; ++d) s = fmaf(Es[u][d], Es[v][d], s);
    G32[p] = s;
  }
}

// per-sample-row scalars: g, a = g^2*|u|^2, basis id ek
__global__ void k_rows(const int* __restrict__ idx1, const int* __restrict__ idx2,
                       const int* __restrict__ i0, const int* __restrict__ i1,
                       const float* __restrict__ g0, const float* __restrict__ g1,
                       const float* __restrict__ G32, float* __restrict__ rowg,
                       float* __restrict__ rowa, int* __restrict__ rowe,
                       int ns, int ncnt, int npad) {
  int r = blockIdx.x * 256 + threadIdx.x;
  if (r >= npad) return;
  float g = 0.f; int ek = 0;
  if (r < ns)        { int t = idx1[r];      ek = i0[t] * 2 + 0; g = g0[t]; }
  else if (r < ncnt) { int t = idx2[r - ns]; ek = i1[t] * 2 + 1; g = g1[t]; }
  rowg[r] = g;
  rowe[r] = ek;
  rowa[r] = g * g * G32[ek * 32 + ek];
}

// bw from analytic sum(d2) = 2n*sum(a) - 2*w^T G w
__global__ void k_prep(const float* __restrict__ rowg, const float* __restrict__ rowa,
                       const int* __restrict__ rowe, const float* __restrict__ G32,
                       float* __restrict__ cl, int ncnt) {
  __shared__ float ws[256 * 33];
  __shared__ double red[256];
  __shared__ float wfin[32];
  int t = threadIdx.x;  // 256
#pragma unroll
  for (int e = 0; e < 32; ++e) ws[t * 33 + e] = 0.f;
  double asum = 0.0;
  for (int r = t; r < ncnt; r += 256) {
    asum += (double)rowa[r];
    ws[t * 33 + rowe[r]] += rowg[r];
  }
  red[t] = asum;
  __syncthreads();
  if (t < 32) {
    float sw = 0.f;
    for (int q = 0; q < 256; ++q) sw += ws[q * 33 + t];
    wfin[t] = sw;
  }
  for (int off = 128; off; off >>= 1) { if (t < off) red[t] += red[t + off]; __syncthreads(); }
  double asum_tot = red[0];
  __syncthreads();
  double part = 0.0;
  for (int i = t; i < 1024; i += 256)
    part += (double)wfin[i >> 5] * (double)wfin[i & 31] * (double)G32[i];
  red[t] = part;
  __syncthreads();
  for (int off = 128; off; off >>= 1) { if (t < off) red[t] += red[t + off]; __syncthreads(); }
  if (t == 0) {
    double nn = (double)ncnt;
    double sumd2 = 2.0 * nn * asum_tot - 2.0 * red[0];
    double bw = sumd2 / (nn * nn - nn) / 4.0;
#pragma unroll
    for (int l = 0; l < 5; ++l) cl[l] = (float)(1.0 / (bw * (double)(1 << l)));
  }
}

// fused tail: blocks [0,ntri) = 256x256 mmd tiles (unsorted rows, K2-gather);
//             blocks [ntri, ntri+1024) = token output; last mmd block = final reduce
__global__ __launch_bounds__(512) void k_mmd2(const float* __restrict__ rowg,
                      const float* __restrict__ rowa, const int* __restrict__ rowe,
                      const float* __restrict__ G32, const float* __restrict__ cl,
                      const float* __restrict__ eo,
                      const int* __restrict__ i0, const int* __restrict__ i1,
                      const float* __restrict__ g0, const float* __restrict__ g1,
                      float* __restrict__ out, double* __restrict__ bsum,
                      float* __restrict__ out_dist,
                      int ns, int ncnt, int nt, int ntri, int* __restrict__ counters) {
  int b = blockIdx.x, tid = threadIdx.x;
  if (b >= ntri) {
    int idx = (b - ntri) * 512 + tid;
    int s = idx >> 7, d = idx & (CC - 1);
    out[idx] = g0[s] * eo[(i0[s] * 2 + 0) * CC + d] + g1[s] * eo[(i1[s] * 2 + 1) * CC + d];
    return;
  }
  __shared__ float K2[1056];
  __shared__ float gA[264], aA[264], sA[264];
  __shared__ int   eA[264];
  __shared__ float gB[264], aB[264], sB[264];
  __shared__ int   eB[264];
  __shared__ float wred[8];
  __shared__ double redd[512];
  __shared__ int lastflag;

  int bi = 0, rem = b;
  while (rem >= nt - bi) { rem -= nt - bi; ++bi; }
  int bj = bi + rem;
  const int ib = bi * TB, jb = bj * TB;

  float c = cl[4];
  for (int i = tid; i < 1024; i += 512) K2[(i >> 5) * 33 + (i & 31)] = 2.f * c * G32[i];
  // stage row scalars: row r at p = (r&7)*33 + (r>>3)
  if (tid < TB) {
    int r = tid, p = (r & 7) * 33 + (r >> 3);
    int m = ib + r;
    gA[p] = rowg[m]; aA[p] = c * rowa[m]; eA[p] = rowe[m] * 33;
    sA[p] = (m < ns) ? 1.f : (m < ncnt ? -1.f : 0.f);
  } else {
    int r = tid - TB, p = (r & 7) * 33 + (r >> 3);
    int m = jb + r;
    gB[p] = rowg[m]; aB[p] = c * rowa[m]; eB[p] = rowe[m];
    sB[p] = (m < ns) ? 1.f : (m < ncnt ? -1.f : 0.f);
  }
  __syncthreads();

  int ti = tid & 15, tj = tid >> 4;        // 16 row-groups(16 rows) x 32 col-groups(8 cols)
  float gj[8], Aj[8], sgj[8]; int exj[8];
#pragma unroll
  for (int q = 0; q < 8; ++q) {            // cols j = tj*8+q -> p = q*33 + tj
    int p = q * 33 + tj;
    gj[q] = gB[p]; Aj[q] = aB[p]; exj[q] = eB[p]; sgj[q] = sB[p];
  }
  float gi[16], Ai[16], sgi[16]; int exi[16];
#pragma unroll
  for (int r = 0; r < 16; ++r) {           // rows i = ti*16 + r -> p = (r&7)*33 + ti*2 + (r>>3)
    int p = (r & 7) * 33 + ti * 2 + (r >> 3);
    gi[r] = gA[p]; Ai[r] = aA[p]; exi[r] = eA[p]; sgi[r] = sA[p];
  }

  float tsum = 0.f;
#pragma unroll
  for (int r = 0; r < 16; ++r) {
#pragma unroll
    for (int q = 0; q < 8; ++q) {
      float gg = gi[r] * gj[q];
      float arg = fmaf(K2[exi[r] + exj[q]], gg, -(Ai[r] + Aj[q]));
      float tv = __expf(arg);
      float t2 = tv * tv;   float s5 = tv + t2;
      float t4 = t2 * t2;   s5 += t4;
      float t8 = t4 * t4;   s5 += t8;
      float t16 = t8 * t8;  s5 += t16;
      tsum = fmaf(sgi[r] * sgj[q], s5, tsum);
    }
  }
#pragma unroll
  for (int off = 32; off; off >>= 1) tsum += __shfl_xor(tsum, off);
  if ((tid & 63) == 0) wred[tid >> 6] = tsum;
  __syncthreads();
  if (tid == 0) {
    float sblk = 0.f;
#pragma unroll
    for (int w = 0; w < 8; ++w) sblk += wred[w];
    bsum[b] = (double)sblk * ((bi == bj) ? 1.0 : 2.0);
  }

  // last-mmd-block election -> final reduce (fixed order, deterministic)
  if (tid == 0) {
    __threadfence();
    int old = atomicAdd(&counters[0], 1);
    lastflag = (old == ntri - 1) ? 1 : 0;
  }
  __syncthreads();
  if (!lastflag) return;
  __threadfence();
  double acc = 0.0;
  for (int i = tid; i < ntri; i += 512) acc += bsum[i];
  redd[tid] = acc;
  __syncthreads();
  for (int off = 256; off; off >>= 1) { if (tid < off) redd[tid] += redd[tid + off]; __syncthreads(); }
  if (tid == 0) out_dist[0] = (float)(-redd[0] / ((double)ns * (double)ns));
}

extern "C" void kernel_launch(void* const* d_in, const int* in_sizes, int n_in,
                              void* d_out, int out_size, void* d_ws, size_t ws_size,
                              hipStream_t stream) {
  const float* x  = (const float*)d_in[0];
  const float* noise = (const float*)d_in[1];
  const float* Wr = (const float*)d_in[2];
  const float* W1 = (const float*)d_in[3];
  const float* b1 = (const float*)d_in[4];
  const float* W2 = (const float*)d_in[5];
  const float* b2 = (const float*)d_in[6];
  const float* W3 = (const float*)d_in[7];
  const float* b3 = (const float*)d_in[8];
  const float* W4 = (const float*)d_in[9];
  const float* b4 = (const float*)d_in[10];
  const int* idx1 = (const int*)d_in[11];
  const int* idx2 = (const int*)d_in[12];
  int ns = in_sizes[11];
  int n = 2 * ns;
  int npad = (n + 255) & ~255;
  int nt = npad / TB;
  int ntri = nt * (nt + 1) / 2;

  char* wp = (char*)d_ws;
  size_t off = 0;
  auto alloc = [&](size_t bytes) -> void* {
    void* p = wp + off;
    off += (bytes + 255) & ~(size_t)255;
    return p;
  };
  int*   i0  = (int*)alloc((size_t)S * 4);
  int*   i1  = (int*)alloc((size_t)S * 4);
  float* g0  = (float*)alloc((size_t)S * 4);
  float* g1  = (float*)alloc((size_t)S * 4);
  float* selpart = (float*)alloc((size_t)1024 * 16 * 4);
  int*   list = (int*)alloc((size_t)32 * S * 4);
  int*   cnt  = (int*)alloc(32 * 4);
  float* gpart = (float*)alloc((size_t)8 * 32 * M * 4);
  float* ei  = (float*)alloc((size_t)E * 2 * M * 4);
  float* h1  = (float*)alloc((size_t)E * 2 * H1 * 4);
  float* h2  = (float*)alloc((size_t)E * 2 * H2 * 4);
  float* h3  = (float*)alloc((size_t)E * 2 * H3 * 4);
  float* eo  = (float*)alloc((size_t)E * 2 * CC * 4);
  float* G32 = (float*)alloc((size_t)1024 * 4);
  float* rowg = (float*)alloc((size_t)npad * 4);
  float* rowa = (float*)alloc((size_t)npad * 4);
  int*   rowe = (int*)alloc((size_t)npad * 4);
  float* cl  = (float*)alloc(8 * 4);
  double* bsum = (double*)alloc((size_t)ntri * 8);
  int* counters = (int*)alloc(256);
  (void)ws_size; (void)n_in; (void)out_size;

  float* out      = (float*)d_out;
  float* out_sel0 = out + (size_t)S * CC;
  float* out_bal  = out + (size_t)S * CC + (size_t)S * E * 2;
  float* out_dist = out_bal + 1;

  k_route<<<S / 4, 256, 0, stream>>>(x, noise, Wr, i0, i1, g0, g1, out_sel0, selpart, counters);
  k_balance<<<1, 512, 0, stream>>>(selpart, i0, i1, out_bal);
  k_lists<<<32, 256, 0, stream>>>(i0, i1, g0, g1, list, cnt);
  k_gather<<<1024, 128, 0, stream>>>(x, list, cnt, gpart);
  k_gather_red<<<64, 256, 0, stream>>>(gpart, ei);
  k_layer<M, H1, true><<<(E * H1 + 3) / 4, 256, 0, stream>>>(ei, W1, b1, h1);
  k_layer<H1, H2, true><<<(E * H2 + 3) / 4, 256, 0, stream>>>(h1, W2, b2, h2);
  k_layer<H2, H3, true><<<(E * H3 + 3) / 4, 256, 0, stream>>>(h2, W3, b3, h3);
  k_layer<H3, CC, false><<<(E * CC + 3) / 4, 256, 0, stream>>>(h3, W4, b4, eo);
  k_G<<<1, 256, 0, stream>>>(eo, G32);
  k_rows<<<(npad + 255) / 256, 256, 0, stream>>>(idx1, idx2, i0, i1, g0, g1, G32,
                                                 rowg, rowa, rowe, ns, n, npad);
  k_prep<<<1, 256, 0, stream>>>(rowg, rowa, rowe, G32, cl, n);
  k_mmd2<<<ntri + (S * CC) / 512, 512, 0, stream>>>(rowg, rowa, rowe, G32, cl, eo,
                                                    i0, i1, g0, g1, out, bsum, out_dist,
                                                    ns, n, nt, ntri, counters);
}